// Round 12
// baseline (756.751 us; speedup 1.0000x reference)
//
#include <hip/hip_runtime.h>
#include <hip/hip_bf16.h>
#include <math.h>

#define BATCH 2
#define SEQ   2048
#define DIM   2048
#define NH    16
#define HD    128
#define NROWS (BATCH * SEQ)   // 4096
#define EPS_RMS 1e-6f

typedef unsigned short ushort_t;
typedef unsigned int   uint_t;
typedef __bf16    bf16x8 __attribute__((ext_vector_type(8)));
typedef _Float16  f16x8  __attribute__((ext_vector_type(8)));
typedef float     f32x4  __attribute__((ext_vector_type(4)));

__device__ inline ushort_t f2bf(float f) {
    uint_t u = __builtin_bit_cast(uint_t, f);
    uint_t r = u + 0x7FFFu + ((u >> 16) & 1u);
    return (ushort_t)(r >> 16);
}
__device__ inline ushort_t f2h(float f) {
    return __builtin_bit_cast(ushort_t, (_Float16)f);
}
__device__ inline float h2f(ushort_t h) {
    return (float)__builtin_bit_cast(_Float16, h);
}

// ================= fused fp32 -> fp16 conversion: x + 4 weight matrices
__global__ __launch_bounds__(256) void cvt_all_kernel(
    const float* __restrict__ x,  const float* __restrict__ wq,
    const float* __restrict__ wk, const float* __restrict__ wv,
    const float* __restrict__ wo,
    ushort_t* __restrict__ xh,  ushort_t* __restrict__ wqh,
    ushort_t* __restrict__ wkh, ushort_t* __restrict__ wvh,
    ushort_t* __restrict__ woh)
{
    const int blk = blockIdx.x;
    const float* src; ushort_t* dst; size_t base;
    if (blk < 4096) { src = x; dst = xh; base = (size_t)blk * 2048; }
    else {
        const int r = blk - 4096;
        const int wsel = r >> 11;
        base = (size_t)(r & 2047) * 2048;
        if      (wsel == 0) { src = wq; dst = wqh; }
        else if (wsel == 1) { src = wk; dst = wkh; }
        else if (wsel == 2) { src = wv; dst = wvh; }
        else                { src = wo; dst = woh; }
    }
    const size_t i = base + ((size_t)threadIdx.x << 3);
    float v[8];
    *(float4*)&v[0] = *(const float4*)&src[i];
    *(float4*)&v[4] = *(const float4*)&src[i + 4];
    uint_t pk[4];
#pragma unroll
    for (int j = 0; j < 4; ++j)
        pk[j] = (uint_t)f2h(v[2 * j]) | ((uint_t)f2h(v[2 * j + 1]) << 16);
    *(uint4*)&dst[i] = make_uint4(pk[0], pk[1], pk[2], pk[3]);
}

// ============== fused QKV GEMM — R12: frozen at R10's best-measured form.
// 128x256 tile, BK=64, 8 waves, grid 768 = 3 exact CU rounds, counted
// vmcnt(6), both-sides XOR swizzle (T2), setprio (T5).
__global__ __launch_bounds__(512, 2) void qkv_gemm_kernel(
    const ushort_t* __restrict__ Ah, const ushort_t* __restrict__ Bq,
    const ushort_t* __restrict__ Bk, const ushort_t* __restrict__ Bv,
    ushort_t* __restrict__ Qh, ushort_t* __restrict__ Kh, ushort_t* __restrict__ Vt)
{
    __shared__ __align__(16) ushort_t sA[16384];   // 2 buf x 128 rows x 64 (32 KB)
    __shared__ __align__(16) ushort_t sB[32768];   // 2 buf x 256 rows x 64 (64 KB)
    const int tid  = threadIdx.x;
    const int w    = tid >> 6;
    const int lane = tid & 63;
    const int fr   = lane & 15;
    const int quad = lane >> 4;
    const int wr   = w >> 2;     // 0..1  (64-row slab)
    const int wc   = w & 3;      // 0..3  (64-col slab)

    const int bid   = blockIdx.x;                 // 768 = 8 * 96
    const int nid   = (bid & 7) * 96 + (bid >> 3);
    const int n_blk = nid >> 5;                   // 0..23
    const int m_blk = nid & 31;                   // 0..31
    const int wsel  = n_blk >> 3;                 // 0=Q 1=K 2=V
    const int m0    = m_blk << 7;                 // BM=128
    const int n0    = (n_blk & 7) << 8;           // BN=256
    const ushort_t* __restrict__ Bh = (wsel == 0) ? Bq : (wsel == 1) ? Bk : Bv;

    const int rt  = tid >> 3;                        // 0..63
    const int csw = ((tid & 7) ^ (rt & 7)) << 3;     // swizzled col (elems)
    const size_t abg = (size_t)(m0 + rt) * DIM + csw;
    const size_t bbg = (size_t)(n0 + rt) * DIM + csw;
    const int lw  = w << 9;                          // wave offset in a pass (elems)
    const int axor = (fr & 7) << 4;                  // read-side XOR (bytes)

#define QG(dst, src) __builtin_amdgcn_global_load_lds( \
        (const __attribute__((address_space(1))) uint_t*)(const void*)(src), \
        (__attribute__((address_space(3))) uint_t*)(void*)(dst), 16, 0, 0)
#define QSA(buf, kt, p) QG(sA + ((buf) << 13) + ((p) << 12) + lw, \
                           Ah + abg + ((size_t)(p) << 17) + ((size_t)(kt) << 6))
#define QSB(buf, kt, p) QG(sB + ((buf) << 14) + ((p) << 12) + lw, \
                           Bh + bbg + ((size_t)(p) << 17) + ((size_t)(kt) << 6))

    f32x4 acc[4][4];
#pragma unroll
    for (int mi = 0; mi < 4; ++mi)
#pragma unroll
        for (int ni = 0; ni < 4; ++ni)
            acc[mi][ni] = (f32x4){0.f, 0.f, 0.f, 0.f};

    // prologue: stage tiles 0 and 1 (12 loads/thread), wait for tile 0 (6 left)
#pragma unroll
    for (int p = 0; p < 2; ++p) QSA(0, 0, p);
#pragma unroll
    for (int p = 0; p < 4; ++p) QSB(0, 0, p);
#pragma unroll
    for (int p = 0; p < 2; ++p) QSA(1, 1, p);
#pragma unroll
    for (int p = 0; p < 4; ++p) QSB(1, 1, p);
    asm volatile("s_waitcnt vmcnt(6)" ::: "memory");
    __builtin_amdgcn_sched_barrier(0);
    __builtin_amdgcn_s_barrier();
    __builtin_amdgcn_sched_barrier(0);

#define QPHASE(MB)                                                              \
        {                                                                       \
            f16x8 af[2][2];                                                     \
            _Pragma("unroll")                                                   \
            for (int m2 = 0; m2 < 2; ++m2)                                      \
                _Pragma("unroll")                                               \
                for (int ks = 0; ks < 2; ++ks)                                  \
                    af[m2][ks] = *(const f16x8*)(sAc +                          \
                        (((wr << 6) + (((MB) + m2) << 4) + fr) << 7) +          \
                        (((ks << 6) + (quad << 4)) ^ axor));                    \
            __builtin_amdgcn_s_setprio(1);                                      \
            _Pragma("unroll")                                                   \
            for (int ks = 0; ks < 2; ++ks)                                      \
                _Pragma("unroll")                                               \
                for (int m2 = 0; m2 < 2; ++m2)                                  \
                    _Pragma("unroll")                                           \
                    for (int ni = 0; ni < 4; ++ni)                              \
                        acc[(MB) + m2][ni] = __builtin_amdgcn_mfma_f32_16x16x32_f16( \
                            af[m2][ks], bfr[ni][ks], acc[(MB) + m2][ni], 0, 0, 0); \
            __builtin_amdgcn_s_setprio(0);                                      \
        }                                                                       \
        __builtin_amdgcn_sched_barrier(0);                                      \
        __builtin_amdgcn_s_barrier();                                           \
        __builtin_amdgcn_sched_barrier(0);

    for (int kt = 0; kt < 32; ++kt) {
        const int cur = kt & 1;
        const char* sAc = (const char*)sA + (cur << 14);   // cur * 16384 B
        const char* sBc = (const char*)sB + (cur << 15);   // cur * 32768 B
        const bool pf = (kt < 30);

        f16x8 bfr[4][2];
#pragma unroll
        for (int ni = 0; ni < 4; ++ni) {
            const int brow = (wc << 6) + (ni << 4) + fr;
#pragma unroll
            for (int ks = 0; ks < 2; ++ks)
                bfr[ni][ks] = *(const f16x8*)(sBc + brow * 128 +
                    (((ks << 6) + (quad << 4)) ^ axor));
        }
        QPHASE(0)
        if (pf) { QSB(cur, kt + 2, 0); QSB(cur, kt + 2, 1);
                  QSB(cur, kt + 2, 2); QSB(cur, kt + 2, 3); }
        QPHASE(2)
        if (pf) {
            QSA(cur, kt + 2, 0); QSA(cur, kt + 2, 1);
            asm volatile("s_waitcnt vmcnt(6)" ::: "memory");
        } else {
            asm volatile("s_waitcnt vmcnt(0)" ::: "memory");
        }
        __builtin_amdgcn_sched_barrier(0);
        __builtin_amdgcn_s_barrier();
        __builtin_amdgcn_sched_barrier(0);
    }
#undef QPHASE
#undef QSA
#undef QSB
#undef QG

    if (wsel < 2) {
        ushort_t* __restrict__ C = (wsel == 0) ? Qh : Kh;
#pragma unroll
        for (int mi = 0; mi < 4; ++mi)
#pragma unroll
            for (int ni = 0; ni < 4; ++ni) {
                const int col = n0 + (wc << 6) + (ni << 4) + fr;
#pragma unroll
                for (int r = 0; r < 4; ++r) {
                    const int rowg = m0 + (wr << 6) + (mi << 4) + (quad << 2) + r;
                    C[(size_t)rowg * DIM + col] = f2h(acc[mi][ni][r]);
                }
            }
    } else {
#pragma unroll
        for (int mi = 0; mi < 4; ++mi)
#pragma unroll
            for (int ni = 0; ni < 4; ++ni) {
                const int col = n0 + (wc << 6) + (ni << 4) + fr;
                const int rowg = m0 + (wr << 6) + (mi << 4) + (quad << 2);
                const int bbi = rowg >> 11, tok = rowg & (SEQ - 1);
                const int hh = col >> 7, d = col & (HD - 1);
                uint2 pk;
                pk.x = (uint_t)f2bf(acc[mi][ni][0]) | ((uint_t)f2bf(acc[mi][ni][1]) << 16);
                pk.y = (uint_t)f2bf(acc[mi][ni][2]) | ((uint_t)f2bf(acc[mi][ni][3]) << 16);
                *(uint2*)&Vt[((size_t)(bbi * NH + hh) * HD + d) * SEQ + tok] = pk;
            }
    }
}

// ============== Wo GEMM — same structure, single B, fp32 C + bias.
// Grid 256 = 8 n-panels x 32 m-blocks = EXACTLY 1 round of 256 CUs.
__global__ __launch_bounds__(512, 2) void wo_gemm_kernel(
    const ushort_t* __restrict__ Ah, const ushort_t* __restrict__ Bh,
    const float* __restrict__ bias, float* __restrict__ C)
{
    __shared__ __align__(16) ushort_t sA[16384];
    __shared__ __align__(16) ushort_t sB[32768];
    const int tid  = threadIdx.x;
    const int w    = tid >> 6;
    const int lane = tid & 63;
    const int fr   = lane & 15;
    const int quad = lane >> 4;
    const int wr   = w >> 2;
    const int wc   = w & 3;

    const int bid   = blockIdx.x;                 // 256 = 8 * 32
    const int nid   = (bid & 7) * 32 + (bid >> 3);
    const int n_blk = nid >> 5;                   // 0..7
    const int m_blk = nid & 31;                   // 0..31
    const int m0    = m_blk << 7;                 // BM=128
    const int n0    = n_blk << 8;                 // BN=256

    const int rt  = tid >> 3;
    const int csw = ((tid & 7) ^ (rt & 7)) << 3;
    const size_t abg = (size_t)(m0 + rt) * DIM + csw;
    const size_t bbg = (size_t)(n0 + rt) * DIM + csw;
    const int lw  = w << 9;
    const int axor = (fr & 7) << 4;

#define QG(dst, src) __builtin_amdgcn_global_load_lds( \
        (const __attribute__((address_space(1))) uint_t*)(const void*)(src), \
        (__attribute__((address_space(3))) uint_t*)(void*)(dst), 16, 0, 0)
#define QSA(buf, kt, p) QG(sA + ((buf) << 13) + ((p) << 12) + lw, \
                           Ah + abg + ((size_t)(p) << 17) + ((size_t)(kt) << 6))
#define QSB(buf, kt, p) QG(sB + ((buf) << 14) + ((p) << 12) + lw, \
                           Bh + bbg + ((size_t)(p) << 17) + ((size_t)(kt) << 6))

    f32x4 acc[4][4];
#pragma unroll
    for (int mi = 0; mi < 4; ++mi)
#pragma unroll
        for (int ni = 0; ni < 4; ++ni)
            acc[mi][ni] = (f32x4){0.f, 0.f, 0.f, 0.f};

#pragma unroll
    for (int p = 0; p < 2; ++p) QSA(0, 0, p);
#pragma unroll
    for (int p = 0; p < 4; ++p) QSB(0, 0, p);
#pragma unroll
    for (int p = 0; p < 2; ++p) QSA(1, 1, p);
#pragma unroll
    for (int p = 0; p < 4; ++p) QSB(1, 1, p);
    asm volatile("s_waitcnt vmcnt(6)" ::: "memory");
    __builtin_amdgcn_sched_barrier(0);
    __builtin_amdgcn_s_barrier();
    __builtin_amdgcn_sched_barrier(0);

#define QPHASE(MB)                                                              \
        {                                                                       \
            f16x8 af[2][2];                                                     \
            _Pragma("unroll")                                                   \
            for (int m2 = 0; m2 < 2; ++m2)                                      \
                _Pragma("unroll")                                               \
                for (int ks = 0; ks < 2; ++ks)                                  \
                    af[m2][ks] = *(const f16x8*)(sAc +                          \
                        (((wr << 6) + (((MB) + m2) << 4) + fr) << 7) +          \
                        (((ks << 6) + (quad << 4)) ^ axor));                    \
            __builtin_amdgcn_s_setprio(1);                                      \
            _Pragma("unroll")                                                   \
            for (int ks = 0; ks < 2; ++ks)                                      \
                _Pragma("unroll")                                               \
                for (int m2 = 0; m2 < 2; ++m2)                                  \
                    _Pragma("unroll")                                           \
                    for (int ni = 0; ni < 4; ++ni)                              \
                        acc[(MB) + m2][ni] = __builtin_amdgcn_mfma_f32_16x16x32_f16( \
                            af[m2][ks], bfr[ni][ks], acc[(MB) + m2][ni], 0, 0, 0); \
            __builtin_amdgcn_s_setprio(0);                                      \
        }                                                                       \
        __builtin_amdgcn_sched_barrier(0);                                      \
        __builtin_amdgcn_s_barrier();                                           \
        __builtin_amdgcn_sched_barrier(0);

    for (int kt = 0; kt < 32; ++kt) {
        const int cur = kt & 1;
        const char* sAc = (const char*)sA + (cur << 14);
        const char* sBc = (const char*)sB + (cur << 15);
        const bool pf = (kt < 30);

        f16x8 bfr[4][2];
#pragma unroll
        for (int ni = 0; ni < 4; ++ni) {
            const int brow = (wc << 6) + (ni << 4) + fr;
#pragma unroll
            for (int ks = 0; ks < 2; ++ks)
                bfr[ni][ks] = *(const f16x8*)(sBc + brow * 128 +
                    (((ks << 6) + (quad << 4)) ^ axor));
        }
        QPHASE(0)
        if (pf) { QSB(cur, kt + 2, 0); QSB(cur, kt + 2, 1);
                  QSB(cur, kt + 2, 2); QSB(cur, kt + 2, 3); }
        QPHASE(2)
        if (pf) {
            QSA(cur, kt + 2, 0); QSA(cur, kt + 2, 1);
            asm volatile("s_waitcnt vmcnt(6)" ::: "memory");
        } else {
            asm volatile("s_waitcnt vmcnt(0)" ::: "memory");
        }
        __builtin_amdgcn_sched_barrier(0);
        __builtin_amdgcn_s_barrier();
        __builtin_amdgcn_sched_barrier(0);
    }
#undef QPHASE
#undef QSA
#undef QSB
#undef QG

#pragma unroll
    for (int mi = 0; mi < 4; ++mi)
#pragma unroll
        for (int ni = 0; ni < 4; ++ni) {
            const int col = n0 + (wc << 6) + (ni << 4) + fr;
            const float bv = bias[col];
#pragma unroll
            for (int r = 0; r < 4; ++r) {
                const int rowg = m0 + (wr << 6) + (mi << 4) + (quad << 2) + r;
                C[(size_t)rowg * DIM + col] = acc[mi][ni][r] + bv;
            }
        }
}

// ===================================================================== GEMM (fp32 fallback)
#define BM 64
#define BN 64
#define BK 16

__global__ __launch_bounds__(256) void gemm_nt_kernel(
    const float* __restrict__ A, const float* __restrict__ W,
    const float* __restrict__ bias, float* __restrict__ C,
    const int M, const int N, const int K)
{
    __shared__ float As[BK][BM + 4];
    __shared__ float Bs[BK][BN + 4];
    const int tid = threadIdx.x;
    const int tx = tid & 15;
    const int ty = tid >> 4;
    const int m0 = blockIdx.y * BM;
    const int n0 = blockIdx.x * BN;
    const int ldr = tid >> 2;
    const int ldc = (tid & 3) << 2;

    float acc[4][4] = {};

    for (int k0 = 0; k0 < K; k0 += BK) {
        __syncthreads();
        const float4 av = *(const float4*)&A[(size_t)(m0 + ldr) * K + (k0 + ldc)];
        const float4 wv = *(const float4*)&W[(size_t)(n0 + ldr) * K + (k0 + ldc)];
        As[ldc + 0][ldr] = av.x; As[ldc + 1][ldr] = av.y;
        As[ldc + 2][ldr] = av.z; As[ldc + 3][ldr] = av.w;
        Bs[ldc + 0][ldr] = wv.x; Bs[ldc + 1][ldr] = wv.y;
        Bs[ldc + 2][ldr] = wv.z; Bs[ldc + 3][ldr] = wv.w;
        __syncthreads();
#pragma unroll
        for (int k = 0; k < BK; ++k) {
            const float4 a4 = *(const float4*)&As[k][ty << 2];
            const float4 b4 = *(const float4*)&Bs[k][tx << 2];
            const float aa[4] = {a4.x, a4.y, a4.z, a4.w};
            const float bb[4] = {b4.x, b4.y, b4.z, b4.w};
#pragma unroll
            for (int i = 0; i < 4; ++i)
#pragma unroll
                for (int j = 0; j < 4; ++j)
                    acc[i][j] = fmaf(aa[i], bb[j], acc[i][j]);
        }
    }

#pragma unroll
    for (int i = 0; i < 4; ++i) {
        const int row = m0 + (ty << 2) + i;
        const int col = n0 + (tx << 2);
        float4 ov;
        ov.x = acc[i][0]; ov.y = acc[i][1]; ov.z = acc[i][2]; ov.w = acc[i][3];
        if (bias != nullptr) {
            ov.x += bias[col + 0]; ov.y += bias[col + 1];
            ov.z += bias[col + 2]; ov.w += bias[col + 3];
        }
        *(float4*)&C[(size_t)row * N + col] = ov;
    }
}

// ==================== fused RMS+RoPE for Q and K (fp16 in, bf16 out)
__global__ __launch_bounds__(256) void rmsnorm_rope_qk_kernel(
    const ushort_t* __restrict__ Qh, const float* __restrict__ gq,
    ushort_t* __restrict__ qbh,
    const ushort_t* __restrict__ Kh, const float* __restrict__ gk,
    ushort_t* __restrict__ kbh,
    const float* __restrict__ freqs)
{
    const int r = blockIdx.x;
    const int s = r & (SEQ - 1);
    const int tid = threadIdx.x;
    const int base = tid << 3;
    const bool isQ = (blockIdx.y == 0);
    const ushort_t* T = isQ ? Qh : Kh;
    const float* g = isQ ? gq : gk;
    ushort_t* out  = isQ ? qbh : kbh;
    const float posc = isQ ? 0.088388347648318447f : 1.0f;

    const uint4 raw = *(const uint4*)&T[(size_t)r * DIM + base];
    const ushort_t* rp = (const ushort_t*)&raw;
    float v[8];
#pragma unroll
    for (int i = 0; i < 8; ++i) v[i] = h2f(rp[i]);

    float ss = 0.f;
#pragma unroll
    for (int i = 0; i < 8; ++i) ss += v[i] * v[i];
#pragma unroll
    for (int off = 32; off > 0; off >>= 1) ss += __shfl_down(ss, off);

    __shared__ float wsum[4];
    __shared__ float inv_sh;
    if ((tid & 63) == 0) wsum[tid >> 6] = ss;
    __syncthreads();
    if (tid == 0)
        inv_sh = rsqrtf((wsum[0] + wsum[1] + wsum[2] + wsum[3]) * (1.0f / DIM) + EPS_RMS);
    __syncthreads();
    const float inv = inv_sh * posc;

    float gg[8];
    *(float4*)&gg[0] = *(const float4*)&g[base];
    *(float4*)&gg[4] = *(const float4*)&g[base + 4];
#pragma unroll
    for (int i = 0; i < 8; ++i) v[i] *= inv * gg[i];

    const int p0 = (base & (HD - 1)) >> 1;
#pragma unroll
    for (int pp = 0; pp < 4; ++pp) {
        float sn, cs;
        __sincosf(freqs[(size_t)s * (HD / 2) + p0 + pp], &sn, &cs);
        const float t0 = v[2 * pp], t1 = v[2 * pp + 1];
        v[2 * pp]     = t0 * cs - t1 * sn;
        v[2 * pp + 1] = t0 * sn + t1 * cs;
    }

    uint_t pk[4];
#pragma unroll
    for (int j = 0; j < 4; ++j)
        pk[j] = (uint_t)f2bf(v[2 * j]) | ((uint_t)f2bf(v[2 * j + 1]) << 16);
    *(uint4*)&out[(size_t)r * DIM + base] = make_uint4(pk[0], pk[1], pk[2], pk[3]);
}

// ================================== RMS + RoPE (fp32 in/out, fallback path)
__global__ __launch_bounds__(256) void rmsnorm_rope_kernel(
    float* __restrict__ T, const float* __restrict__ g,
    const float* __restrict__ freqs)
{
    const int r = blockIdx.x;
    const int s = r & (SEQ - 1);
    const int tid = threadIdx.x;
    const int base = tid << 3;

    float v[8];
    *(float4*)&v[0] = *(const float4*)&T[(size_t)r * DIM + base];
    *(float4*)&v[4] = *(const float4*)&T[(size_t)r * DIM + base + 4];

    float ss = 0.f;
#pragma unroll
    for (int i = 0; i < 8; ++i) ss += v[i] * v[i];
#pragma unroll
    for (int off = 32; off > 0; off >>= 1) ss += __shfl_down(ss, off);

    __shared__ float wsum[4];
    __shared__ float inv_sh;
    if ((tid & 63) == 0) wsum[tid >> 6] = ss;
    __syncthreads();
    if (tid == 0)
        inv_sh = rsqrtf((wsum[0] + wsum[1] + wsum[2] + wsum[3]) * (1.0f / DIM) + EPS_RMS);
    __syncthreads();
    const float inv = inv_sh;

    float gg[8];
    *(float4*)&gg[0] = *(const float4*)&g[base];
    *(float4*)&gg[4] = *(const float4*)&g[base + 4];
#pragma unroll
    for (int i = 0; i < 8; ++i) v[i] *= inv * gg[i];

    const int p0 = (base & (HD - 1)) >> 1;
#pragma unroll
    for (int pp = 0; pp < 4; ++pp) {
        float sn, cs;
        __sincosf(freqs[(size_t)s * (HD / 2) + p0 + pp], &sn, &cs);
        const float t0 = v[2 * pp], t1 = v[2 * pp + 1];
        v[2 * pp]     = t0 * cs - t1 * sn;
        v[2 * pp + 1] = t0 * sn + t1 * cs;
    }

    *(float4*)&T[(size_t)r * DIM + base]     = *(float4*)&v[0];
    *(float4*)&T[(size_t)r * DIM + base + 4] = *(float4*)&v[4];
}

// ======================================================== MFMA flash attention
// R12: NO K/V LDS staging (catalog lesson #7 — K/V is L2-resident, FETCH 23MB
// proved in R3). K and V fragments read DIRECTLY from global (L2 hit ~200cy).
// sP is wave-private -> ZERO barriers in the main loop; kernel is fully
// wave-independent. LDS 54KB -> 18.4KB; (256,4) = 4 blocks/CU = 16 waves.
// XCD swizzle + T13 defer-max + T5 setprio kept.
#define AQ 128
#define AK 64
#define VSTR 72    // sP row stride (elems): 144 B
#define RESCALE_THR 8.0f

__global__ __launch_bounds__(256, 4) void attn_mfma_kernel(
    const ushort_t* __restrict__ QH, const ushort_t* __restrict__ KH,
    const ushort_t* __restrict__ VtG, const int* __restrict__ seq_lens,
    ushort_t* __restrict__ Oh)
{
    __shared__ __align__(16) ushort_t sP[AQ * VSTR];    // [query][key] (wave-private rows)

    const int tid  = threadIdx.x;
    const int w    = tid >> 6;
    const int lane = tid & 63;
    const int fr   = lane & 15;
    const int quad = lane >> 4;

    // XCD swizzle: 64 consecutive swizzled ids per XCD = 4 (b,h) K/V streams
    const int bid = blockIdx.x;
    const int sw  = (bid & 7) * 64 + (bid >> 3);
    const int q0  = (sw & 15) * AQ;
    const int hb  = sw >> 4;          // 0..31
    const int h   = hb & 15;
    const int b   = hb >> 4;
    const int len = seq_lens[b];

    bf16x8 qfrag[2][4];
#pragma unroll
    for (int qt = 0; qt < 2; ++qt)
#pragma unroll
        for (int h4 = 0; h4 < 4; ++h4) {
            const size_t qrow = (size_t)(b * SEQ + q0 + (w << 5) + (qt << 4) + fr);
            qfrag[qt][h4] = *(const bf16x8*)&QH[qrow * DIM + h * HD + (h4 << 5) + (quad << 3)];
        }

    f32x4 Oacc[2][8];
#pragma unroll
    for (int qt = 0; qt < 2; ++qt)
#pragma unroll
        for (int dt = 0; dt < 8; ++dt)
            Oacc[qt][dt] = (f32x4){0.f, 0.f, 0.f, 0.f};
    float mrow[2] = {-1.0e30f, -1.0e30f};
    float lrow[2] = {0.f, 0.f};

    // direct-from-L2 fragment bases
    const size_t kfb = (size_t)(b * SEQ) * DIM + h * HD + (quad << 3);     // + (k0+kt*16+fr)*DIM + h4*32
    const size_t vfb = ((size_t)(b * NH + h) * HD + fr) * SEQ + (quad << 3); // + dt*16*SEQ + k0 + ks*32

    const int ntiles = (len + AK - 1) / AK;
    for (int t = 0; t < ntiles; ++t) {
        const int k0 = t * AK;
        const bool masked = (k0 + AK > len);   // wave-uniform

        // ---- QK^T: K fragments straight from L2
        f32x4 S[4][2];
        __builtin_amdgcn_s_setprio(1);
#pragma unroll
        for (int kt = 0; kt < 4; ++kt) {
            bf16x8 kf[4];
#pragma unroll
            for (int h4 = 0; h4 < 4; ++h4)
                kf[h4] = *(const bf16x8*)&KH[kfb + (size_t)(k0 + (kt << 4) + fr) * DIM + (h4 << 5)];
#pragma unroll
            for (int qt = 0; qt < 2; ++qt) {
                f32x4 a = (f32x4){0.f, 0.f, 0.f, 0.f};
#pragma unroll
                for (int h4 = 0; h4 < 4; ++h4)
                    a = __builtin_amdgcn_mfma_f32_16x16x32_bf16(kf[h4], qfrag[qt][h4], a, 0, 0, 0);
                S[kt][qt] = a;
            }
        }
        __builtin_amdgcn_s_setprio(0);

        // ---- online softmax (wave-local; sP rows are wave-private)
#pragma unroll
        for (int qt = 0; qt < 2; ++qt) {
            float tm = -1.0e30f;
            if (masked) {
#pragma unroll
                for (int kt = 0; kt < 4; ++kt)
#pragma unroll
                    for (int r = 0; r < 4; ++r) {
                        const int key = k0 + (kt << 4) + (quad << 2) + r;
                        float s = (key < len) ? S[kt][qt][r] : -1.0e30f;
                        S[kt][qt][r] = s;
                        tm = fmaxf(tm, s);
                    }
            } else {
#pragma unroll
                for (int kt = 0; kt < 4; ++kt)
#pragma unroll
                    for (int r = 0; r < 4; ++r)
                        tm = fmaxf(tm, S[kt][qt][r]);
            }
            tm = fmaxf(tm, __shfl_xor(tm, 16));
            tm = fmaxf(tm, __shfl_xor(tm, 32));

            float mnew;
            if (__all(tm - mrow[qt] <= RESCALE_THR)) {
                mnew = mrow[qt];
            } else {
                mnew = fmaxf(mrow[qt], tm);
                const float alpha = __expf(mrow[qt] - mnew);
                mrow[qt] = mnew;
                lrow[qt] *= alpha;
#pragma unroll
                for (int r = 0; r < 4; ++r) {
                    const float ar = __shfl(alpha, (quad << 2) + r);
#pragma unroll
                    for (int dt = 0; dt < 8; ++dt)
                        Oacc[qt][dt][r] *= ar;
                }
            }

            float rsum = 0.f;
#pragma unroll
            for (int kt = 0; kt < 4; ++kt) {
                float p[4];
#pragma unroll
                for (int r = 0; r < 4; ++r) {
                    p[r] = __expf(S[kt][qt][r] - mnew);
                    rsum += p[r];
                }
                uint2 pk;
                pk.x = (uint_t)f2bf(p[0]) | ((uint_t)f2bf(p[1]) << 16);
                pk.y = (uint_t)f2bf(p[2]) | ((uint_t)f2bf(p[3]) << 16);
                *(uint2*)&sP[((w << 5) + (qt << 4) + fr) * VSTR + (kt << 4) + (quad << 2)] = pk;
            }
            rsum += __shfl_xor(rsum, 16);
            rsum += __shfl_xor(rsum, 32);
            lrow[qt] += rsum;
        }

        // ---- PV: V fragments straight from L2, P from wave-private LDS
        __builtin_amdgcn_s_setprio(1);
#pragma unroll
        for (int ks = 0; ks < 2; ++ks) {
            bf16x8 pf[2];
#pragma unroll
            for (int qt = 0; qt < 2; ++qt)
                pf[qt] = *(const bf16x8*)&sP[((w << 5) + (qt << 4) + fr) * VSTR + (ks << 5) + (quad << 3)];
#pragma unroll
            for (int dt = 0; dt < 8; ++dt) {
                const bf16x8 vf = *(const bf16x8*)&VtG[vfb + (size_t)(dt << 4) * SEQ + k0 + (ks << 5)];
#pragma unroll
                for (int qt = 0; qt < 2; ++qt)
                    Oacc[qt][dt] = __builtin_amdgcn_mfma_f32_16x16x32_bf16(pf[qt], vf, Oacc[qt][dt], 0, 0, 0);
            }
        }
        __builtin_amdgcn_s_setprio(0);
    }

    // ---- writeout (fp16, feeds final GEMM A-side directly)
#pragma unroll
    for (int qt = 0; qt < 2; ++qt) {
        float linv[4];
#pragma unroll
        for (int r = 0; r < 4; ++r)
            linv[r] = 1.0f / __shfl(lrow[qt], (quad << 2) + r);
#pragma unroll
        for (int dt = 0; dt < 8; ++dt)
#pragma unroll
            for (int r = 0; r < 4; ++r) {
                const int qrow = q0 + (w << 5) + (qt << 4) + (quad << 2) + r;
                Oh[(size_t)(b * SEQ + qrow) * DIM + h * HD + (dt << 4) + fr] =
                    f2h(Oacc[qt][dt][r] * linv[r]);
            }
    }
}

// ======================================== fp32 flash attention (fallback)
#define BQ  64
#define BKT 64

__global__ __launch_bounds__(256) void attn_kernel(
    const float* __restrict__ Q, const float* __restrict__ K,
    const float* __restrict__ V, const int* __restrict__ seq_lens,
    float* __restrict__ O)
{
    const int qt = blockIdx.x;
    const int h  = blockIdx.y;
    const int b  = blockIdx.z;
    const int len = seq_lens[b];
    const int q0 = qt * BQ;
    const float scale = 0.088388347648318447f;

    __shared__ float Qst[HD][BQ + 4];
    __shared__ float Kst[HD][BKT + 4];
    __shared__ float Vs[BKT][HD + 4];
    __shared__ float Sc[BQ][BKT + 1];
    __shared__ float mrow[BQ], lrow[BQ], alpha_s[BQ];

    const int tid = threadIdx.x;
    const int si0 = (tid >> 4) << 2;
    const int sj0 = (tid & 15) << 2;
    const int pi0 = (tid >> 4) << 2;
    const int pc0 = (tid & 15) << 3;

    for (int i = tid; i < BQ * HD / 4; i += 256) {
        const int e = i << 2;
        const int row = e >> 7;
        const int c0 = e & (HD - 1);
        const float4 qv = *(const float4*)&Q[(size_t)(b * SEQ + q0 + row) * DIM + h * HD + c0];
        Qst[c0 + 0][row] = qv.x; Qst[c0 + 1][row] = qv.y;
        Qst[c0 + 2][row] = qv.z; Qst[c0 + 3][row] = qv.w;
    }
    if (tid < BQ) { mrow[tid] = -3.0e38f; lrow[tid] = 0.f; }

    float o[4][8] = {};
    __syncthreads();

    const int ntiles = (len + BKT - 1) / BKT;
    for (int t = 0; t < ntiles; ++t) {
        const int k0 = t * BKT;
        __syncthreads();
        for (int i = tid; i < BKT * HD / 4; i += 256) {
            const int e = i << 2;
            const int row = e >> 7;
            const int c0 = e & (HD - 1);
            const int kg = k0 + row;
            float4 kv = make_float4(0.f, 0.f, 0.f, 0.f);
            float4 vv = make_float4(0.f, 0.f, 0.f, 0.f);
            if (kg < len) {
                kv = *(const float4*)&K[(size_t)(b * SEQ + kg) * DIM + h * HD + c0];
                vv = *(const float4*)&V[(size_t)(b * SEQ + kg) * DIM + h * HD + c0];
            }
            Kst[c0 + 0][row] = kv.x; Kst[c0 + 1][row] = kv.y;
            Kst[c0 + 2][row] = kv.z; Kst[c0 + 3][row] = kv.w;
            *(float4*)&Vs[row][c0] = vv;
        }
        __syncthreads();

        float acc[4][4] = {};
#pragma unroll 8
        for (int kk = 0; kk < HD; ++kk) {
            const float4 q4 = *(const float4*)&Qst[kk][si0];
            const float4 k4 = *(const float4*)&Kst[kk][sj0];
            const float qa[4] = {q4.x, q4.y, q4.z, q4.w};
            const float ka[4] = {k4.x, k4.y, k4.z, k4.w};
#pragma unroll
            for (int i = 0; i < 4; ++i)
#pragma unroll
                for (int j = 0; j < 4; ++j)
                    acc[i][j] = fmaf(qa[i], ka[j], acc[i][j]);
        }
#pragma unroll
        for (int i = 0; i < 4; ++i)
#pragma unroll
            for (int j = 0; j < 4; ++j) {
                const int jg = k0 + sj0 + j;
                Sc[si0 + i][sj0 + j] = (jg < len) ? acc[i][j] * scale : -1.0e9f;
            }
        __syncthreads();

        if (tid < BQ) {
            const int i = tid;
            const float m_old = mrow[i];
            float mx = m_old;
            for (int j = 0; j < BKT; ++j) mx = fmaxf(mx, Sc[i][j]);
            const float al = __expf(m_old - mx);
            float sum = 0.f;
            for (int j = 0; j < BKT; ++j) {
                const float p = __expf(Sc[i][j] - mx);
                Sc[i][j] = p;
                sum += p;
            }
            mrow[i] = mx;
            lrow[i] = lrow[i] * al + sum;
            alpha_s[i] = al;
        }
        __syncthreads();

#pragma unroll
        for (int i = 0; i < 4; ++i) {
            const float al = alpha_s[pi0 + i];
#pragma unroll
            for (int c = 0; c < 8; ++c) o[i][c] *= al;
        }
        for (int j = 0; j < BKT; ++j) {
            float p[4];
#pragma unroll
            for (int i = 0; i < 4; ++i) p[i] = Sc[pi0 + i][j];
            const float4 v0 = *(const float4*)&Vs[j][pc0];
            const float4 v1 = *(const float4*)&Vs[j][pc0 + 4];
            const float va[8] = {v0.x, v0.y, v0.z, v0.w, v1.x, v1.y, v1.z, v1.w};
#pragma unroll
            for (int i = 0; i < 4; ++i)
#pragma unroll
                for (int c = 0; c < 8; ++c)
                    o[i][c] = fmaf(p[i], va[c], o[i][c]);
        }
    }

#pragma unroll
    for (int i = 0; i < 4; ++i) {
        const float invl = 1.0f / lrow[pi0 + i];
        float4 w0, w1;
        w0.x = o[i][0] * invl; w0.y = o[i][1] * invl;
        w0.z = o[i][2] * invl; w0.w = o[i][3] * invl;
        w1.x = o[i][4] * invl; w1.y = o[i][5] * invl;
        w1.z = o[i][6] * invl; w1.w = o[i][7] * invl;
        float* op = &O[(size_t)(b * SEQ + q0 + pi0 + i) * DIM + h * HD + pc0];
        *(float4*)&op[0] = w0;
        *(float4*)&op[4] = w1;
    }
}

// ==================================================================== launch
extern "C" void kernel_launch(void* const* d_in, const int* in_sizes, int n_in,
                              void* d_out, int out_size, void* d_ws, size_t ws_size,
                              hipStream_t stream)
{
    const float* x        = (const float*)d_in[0];
    const int*   seq_lens = (const int*)d_in[1];
    const float* freqs    = (const float*)d_in[3];
    const float* Wq       = (const float*)d_in[4];
    const float* Wk       = (const float*)d_in[5];
    const float* Wv       = (const float*)d_in[6];
    const float* Wo       = (const float*)d_in[7];
    const float* bo       = (const float*)d_in[8];
    const float* gq       = (const float*)d_in[9];
    const float* gk       = (const float*)d_in[10];
    float* out = (float*)d_out;

    const size_t mat = (size_t)NROWS * DIM;       // 8.39M elems
    const size_t wsz = (size_t)DIM * DIM;         // 4.19M elems

    // ---- MFMA-path workspace layout (fp16 Q/K; layout superset of old) ----
    ushort_t* qh16 = (ushort_t*)d_ws;              // mat fp16 (Q pre-norm)
    ushort_t* kh16 = qh16 + mat;                   // mat fp16 (K pre-norm)
    ushort_t* xh   = kh16 + 3 * mat;               // keep old offsets
    ushort_t* wqh  = xh + mat;                     // 4 x wsz fp16 weights
    ushort_t* wkh  = wqh + wsz;
    ushort_t* wvh  = wkh + wsz;
    ushort_t* woh  = wvh + wsz;
    ushort_t* qbh  = woh + wsz;                    // mat bf16 (Q, pre-scaled)
    ushort_t* kbh  = qbh + mat;                    // mat bf16
    ushort_t* vtg  = kbh + mat;                    // mat bf16 (transposed V)
    ushort_t* abh  = vtg + mat;                    // mat fp16 (attn out)

    const size_t need = 2 * mat * sizeof(float)
                      + (mat + 4 * wsz + 4 * mat) * sizeof(ushort_t);

    if (ws_size >= need) {
        // ================= plain-fp16 MFMA path =================
        cvt_all_kernel<<<12288, 256, 0, stream>>>(
            x, Wq, Wk, Wv, Wo, xh, wqh, wkh, wvh, woh);

        qkv_gemm_kernel<<<768, 512, 0, stream>>>(xh, wqh, wkh, wvh, qh16, kh16, vtg);

        rmsnorm_rope_qk_kernel<<<dim3(NROWS, 2), 256, 0, stream>>>(
            qh16, gq, qbh, kh16, gk, kbh, freqs);

        attn_mfma_kernel<<<512, 256, 0, stream>>>(qbh, kbh, vtg, seq_lens, abh);

        wo_gemm_kernel<<<256, 512, 0, stream>>>(abh, woh, bo, out);
    } else {
        // ================= fp32 fallback (134 MB) =================
        float* Qb = (float*)d_ws;
        float* Kb = Qb + mat;
        float* Vb = Kb + mat;
        float* Ab = Vb + mat;
        const dim3 gemm_grid(DIM / BN, NROWS / BM);
        gemm_nt_kernel<<<gemm_grid, 256, 0, stream>>>(x, Wq, nullptr, Qb, NROWS, DIM, DIM);
        gemm_nt_kernel<<<gemm_grid, 256, 0, stream>>>(x, Wk, nullptr, Kb, NROWS, DIM, DIM);
        gemm_nt_kernel<<<gemm_grid, 256, 0, stream>>>(x, Wv, nullptr, Vb, NROWS, DIM, DIM);
        rmsnorm_rope_kernel<<<NROWS, 256, 0, stream>>>(Qb, gq, freqs);
        rmsnorm_rope_kernel<<<NROWS, 256, 0, stream>>>(Kb, gk, freqs);
        attn_kernel<<<dim3(SEQ / BQ, NH, BATCH), 256, 0, stream>>>(Qb, Kb, Vb, seq_lens, Ab);
        gemm_nt_kernel<<<gemm_grid, 256, 0, stream>>>(Ab, Wo, bo, out, NROWS, DIM, DIM);
    }
}

// Round 13
// 447.979 us; speedup vs baseline: 1.6893x; 1.6893x over previous
//
#include <hip/hip_runtime.h>
#include <hip/hip_bf16.h>
#include <math.h>

#define BATCH 2
#define SEQ   2048
#define DIM   2048
#define NH    16
#define HD    128
#define NROWS (BATCH * SEQ)   // 4096
#define EPS_RMS 1e-6f

typedef unsigned short ushort_t;
typedef unsigned int   uint_t;
typedef __bf16    bf16x8 __attribute__((ext_vector_type(8)));
typedef _Float16  f16x8  __attribute__((ext_vector_type(8)));
typedef float     f32x4  __attribute__((ext_vector_type(4)));

__device__ inline ushort_t f2bf(float f) {
    uint_t u = __builtin_bit_cast(uint_t, f);
    uint_t r = u + 0x7FFFu + ((u >> 16) & 1u);
    return (ushort_t)(r >> 16);
}
__device__ inline ushort_t f2h(float f) {
    return __builtin_bit_cast(ushort_t, (_Float16)f);
}
__device__ inline float h2f(ushort_t h) {
    return (float)__builtin_bit_cast(_Float16, h);
}

// ================= fused fp32 -> fp16 conversion: x + 4 weight matrices
__global__ __launch_bounds__(256) void cvt_all_kernel(
    const float* __restrict__ x,  const float* __restrict__ wq,
    const float* __restrict__ wk, const float* __restrict__ wv,
    const float* __restrict__ wo,
    ushort_t* __restrict__ xh,  ushort_t* __restrict__ wqh,
    ushort_t* __restrict__ wkh, ushort_t* __restrict__ wvh,
    ushort_t* __restrict__ woh)
{
    const int blk = blockIdx.x;
    const float* src; ushort_t* dst; size_t base;
    if (blk < 4096) { src = x; dst = xh; base = (size_t)blk * 2048; }
    else {
        const int r = blk - 4096;
        const int wsel = r >> 11;
        base = (size_t)(r & 2047) * 2048;
        if      (wsel == 0) { src = wq; dst = wqh; }
        else if (wsel == 1) { src = wk; dst = wkh; }
        else if (wsel == 2) { src = wv; dst = wvh; }
        else                { src = wo; dst = woh; }
    }
    const size_t i = base + ((size_t)threadIdx.x << 3);
    float v[8];
    *(float4*)&v[0] = *(const float4*)&src[i];
    *(float4*)&v[4] = *(const float4*)&src[i + 4];
    uint_t pk[4];
#pragma unroll
    for (int j = 0; j < 4; ++j)
        pk[j] = (uint_t)f2h(v[2 * j]) | ((uint_t)f2h(v[2 * j + 1]) << 16);
    *(uint4*)&dst[i] = make_uint4(pk[0], pk[1], pk[2], pk[3]);
}

// ============== fused QKV GEMM — best-measured form (R10, 148.0 us):
// 128x256 tile, BK=64, 8 waves, grid 768 = 3 exact CU rounds, counted
// vmcnt(6), both-sides XOR swizzle (T2), setprio (T5).
__global__ __launch_bounds__(512, 2) void qkv_gemm_kernel(
    const ushort_t* __restrict__ Ah, const ushort_t* __restrict__ Bq,
    const ushort_t* __restrict__ Bk, const ushort_t* __restrict__ Bv,
    ushort_t* __restrict__ Qh, ushort_t* __restrict__ Kh, ushort_t* __restrict__ Vt)
{
    __shared__ __align__(16) ushort_t sA[16384];   // 2 buf x 128 rows x 64 (32 KB)
    __shared__ __align__(16) ushort_t sB[32768];   // 2 buf x 256 rows x 64 (64 KB)
    const int tid  = threadIdx.x;
    const int w    = tid >> 6;
    const int lane = tid & 63;
    const int fr   = lane & 15;
    const int quad = lane >> 4;
    const int wr   = w >> 2;     // 0..1  (64-row slab)
    const int wc   = w & 3;      // 0..3  (64-col slab)

    const int bid   = blockIdx.x;                 // 768 = 8 * 96
    const int nid   = (bid & 7) * 96 + (bid >> 3);
    const int n_blk = nid >> 5;                   // 0..23
    const int m_blk = nid & 31;                   // 0..31
    const int wsel  = n_blk >> 3;                 // 0=Q 1=K 2=V
    const int m0    = m_blk << 7;                 // BM=128
    const int n0    = (n_blk & 7) << 8;           // BN=256
    const ushort_t* __restrict__ Bh = (wsel == 0) ? Bq : (wsel == 1) ? Bk : Bv;

    const int rt  = tid >> 3;                        // 0..63
    const int csw = ((tid & 7) ^ (rt & 7)) << 3;     // swizzled col (elems)
    const size_t abg = (size_t)(m0 + rt) * DIM + csw;
    const size_t bbg = (size_t)(n0 + rt) * DIM + csw;
    const int lw  = w << 9;                          // wave offset in a pass (elems)
    const int axor = (fr & 7) << 4;                  // read-side XOR (bytes)

#define QG(dst, src) __builtin_amdgcn_global_load_lds( \
        (const __attribute__((address_space(1))) uint_t*)(const void*)(src), \
        (__attribute__((address_space(3))) uint_t*)(void*)(dst), 16, 0, 0)
#define QSA(buf, kt, p) QG(sA + ((buf) << 13) + ((p) << 12) + lw, \
                           Ah + abg + ((size_t)(p) << 17) + ((size_t)(kt) << 6))
#define QSB(buf, kt, p) QG(sB + ((buf) << 14) + ((p) << 12) + lw, \
                           Bh + bbg + ((size_t)(p) << 17) + ((size_t)(kt) << 6))

    f32x4 acc[4][4];
#pragma unroll
    for (int mi = 0; mi < 4; ++mi)
#pragma unroll
        for (int ni = 0; ni < 4; ++ni)
            acc[mi][ni] = (f32x4){0.f, 0.f, 0.f, 0.f};

    // prologue: stage tiles 0 and 1 (12 loads/thread), wait for tile 0 (6 left)
#pragma unroll
    for (int p = 0; p < 2; ++p) QSA(0, 0, p);
#pragma unroll
    for (int p = 0; p < 4; ++p) QSB(0, 0, p);
#pragma unroll
    for (int p = 0; p < 2; ++p) QSA(1, 1, p);
#pragma unroll
    for (int p = 0; p < 4; ++p) QSB(1, 1, p);
    asm volatile("s_waitcnt vmcnt(6)" ::: "memory");
    __builtin_amdgcn_sched_barrier(0);
    __builtin_amdgcn_s_barrier();
    __builtin_amdgcn_sched_barrier(0);

#define QPHASE(MB)                                                              \
        {                                                                       \
            f16x8 af[2][2];                                                     \
            _Pragma("unroll")                                                   \
            for (int m2 = 0; m2 < 2; ++m2)                                      \
                _Pragma("unroll")                                               \
                for (int ks = 0; ks < 2; ++ks)                                  \
                    af[m2][ks] = *(const f16x8*)(sAc +                          \
                        (((wr << 6) + (((MB) + m2) << 4) + fr) << 7) +          \
                        (((ks << 6) + (quad << 4)) ^ axor));                    \
            __builtin_amdgcn_s_setprio(1);                                      \
            _Pragma("unroll")                                                   \
            for (int ks = 0; ks < 2; ++ks)                                      \
                _Pragma("unroll")                                               \
                for (int m2 = 0; m2 < 2; ++m2)                                  \
                    _Pragma("unroll")                                           \
                    for (int ni = 0; ni < 4; ++ni)                              \
                        acc[(MB) + m2][ni] = __builtin_amdgcn_mfma_f32_16x16x32_f16( \
                            af[m2][ks], bfr[ni][ks], acc[(MB) + m2][ni], 0, 0, 0); \
            __builtin_amdgcn_s_setprio(0);                                      \
        }                                                                       \
        __builtin_amdgcn_sched_barrier(0);                                      \
        __builtin_amdgcn_s_barrier();                                           \
        __builtin_amdgcn_sched_barrier(0);

    for (int kt = 0; kt < 32; ++kt) {
        const int cur = kt & 1;
        const char* sAc = (const char*)sA + (cur << 14);   // cur * 16384 B
        const char* sBc = (const char*)sB + (cur << 15);   // cur * 32768 B
        const bool pf = (kt < 30);

        f16x8 bfr[4][2];
#pragma unroll
        for (int ni = 0; ni < 4; ++ni) {
            const int brow = (wc << 6) + (ni << 4) + fr;
#pragma unroll
            for (int ks = 0; ks < 2; ++ks)
                bfr[ni][ks] = *(const f16x8*)(sBc + brow * 128 +
                    (((ks << 6) + (quad << 4)) ^ axor));
        }
        QPHASE(0)
        if (pf) { QSB(cur, kt + 2, 0); QSB(cur, kt + 2, 1);
                  QSB(cur, kt + 2, 2); QSB(cur, kt + 2, 3); }
        QPHASE(2)
        if (pf) {
            QSA(cur, kt + 2, 0); QSA(cur, kt + 2, 1);
            asm volatile("s_waitcnt vmcnt(6)" ::: "memory");
        } else {
            asm volatile("s_waitcnt vmcnt(0)" ::: "memory");
        }
        __builtin_amdgcn_sched_barrier(0);
        __builtin_amdgcn_s_barrier();
        __builtin_amdgcn_sched_barrier(0);
    }
#undef QPHASE
#undef QSA
#undef QSB
#undef QG

    if (wsel < 2) {
        ushort_t* __restrict__ C = (wsel == 0) ? Qh : Kh;
#pragma unroll
        for (int mi = 0; mi < 4; ++mi)
#pragma unroll
            for (int ni = 0; ni < 4; ++ni) {
                const int col = n0 + (wc << 6) + (ni << 4) + fr;
#pragma unroll
                for (int r = 0; r < 4; ++r) {
                    const int rowg = m0 + (wr << 6) + (mi << 4) + (quad << 2) + r;
                    C[(size_t)rowg * DIM + col] = f2h(acc[mi][ni][r]);
                }
            }
    } else {
#pragma unroll
        for (int mi = 0; mi < 4; ++mi)
#pragma unroll
            for (int ni = 0; ni < 4; ++ni) {
                const int col = n0 + (wc << 6) + (ni << 4) + fr;
                const int rowg = m0 + (wr << 6) + (mi << 4) + (quad << 2);
                const int bbi = rowg >> 11, tok = rowg & (SEQ - 1);
                const int hh = col >> 7, d = col & (HD - 1);
                uint2 pk;
                pk.x = (uint_t)f2bf(acc[mi][ni][0]) | ((uint_t)f2bf(acc[mi][ni][1]) << 16);
                pk.y = (uint_t)f2bf(acc[mi][ni][2]) | ((uint_t)f2bf(acc[mi][ni][3]) << 16);
                *(uint2*)&Vt[((size_t)(bbi * NH + hh) * HD + d) * SEQ + tok] = pk;
            }
    }
}

// ============== Wo GEMM — same structure, single B, fp32 C + bias.
// Grid 256 = 8 n-panels x 32 m-blocks = EXACTLY 1 round of 256 CUs.
__global__ __launch_bounds__(512, 2) void wo_gemm_kernel(
    const ushort_t* __restrict__ Ah, const ushort_t* __restrict__ Bh,
    const float* __restrict__ bias, float* __restrict__ C)
{
    __shared__ __align__(16) ushort_t sA[16384];
    __shared__ __align__(16) ushort_t sB[32768];
    const int tid  = threadIdx.x;
    const int w    = tid >> 6;
    const int lane = tid & 63;
    const int fr   = lane & 15;
    const int quad = lane >> 4;
    const int wr   = w >> 2;
    const int wc   = w & 3;

    const int bid   = blockIdx.x;                 // 256 = 8 * 32
    const int nid   = (bid & 7) * 32 + (bid >> 3);
    const int n_blk = nid >> 5;                   // 0..7
    const int m_blk = nid & 31;                   // 0..31
    const int m0    = m_blk << 7;                 // BM=128
    const int n0    = n_blk << 8;                 // BN=256

    const int rt  = tid >> 3;
    const int csw = ((tid & 7) ^ (rt & 7)) << 3;
    const size_t abg = (size_t)(m0 + rt) * DIM + csw;
    const size_t bbg = (size_t)(n0 + rt) * DIM + csw;
    const int lw  = w << 9;
    const int axor = (fr & 7) << 4;

#define QG(dst, src) __builtin_amdgcn_global_load_lds( \
        (const __attribute__((address_space(1))) uint_t*)(const void*)(src), \
        (__attribute__((address_space(3))) uint_t*)(void*)(dst), 16, 0, 0)
#define QSA(buf, kt, p) QG(sA + ((buf) << 13) + ((p) << 12) + lw, \
                           Ah + abg + ((size_t)(p) << 17) + ((size_t)(kt) << 6))
#define QSB(buf, kt, p) QG(sB + ((buf) << 14) + ((p) << 12) + lw, \
                           Bh + bbg + ((size_t)(p) << 17) + ((size_t)(kt) << 6))

    f32x4 acc[4][4];
#pragma unroll
    for (int mi = 0; mi < 4; ++mi)
#pragma unroll
        for (int ni = 0; ni < 4; ++ni)
            acc[mi][ni] = (f32x4){0.f, 0.f, 0.f, 0.f};

#pragma unroll
    for (int p = 0; p < 2; ++p) QSA(0, 0, p);
#pragma unroll
    for (int p = 0; p < 4; ++p) QSB(0, 0, p);
#pragma unroll
    for (int p = 0; p < 2; ++p) QSA(1, 1, p);
#pragma unroll
    for (int p = 0; p < 4; ++p) QSB(1, 1, p);
    asm volatile("s_waitcnt vmcnt(6)" ::: "memory");
    __builtin_amdgcn_sched_barrier(0);
    __builtin_amdgcn_s_barrier();
    __builtin_amdgcn_sched_barrier(0);

#define QPHASE(MB)                                                              \
        {                                                                       \
            f16x8 af[2][2];                                                     \
            _Pragma("unroll")                                                   \
            for (int m2 = 0; m2 < 2; ++m2)                                      \
                _Pragma("unroll")                                               \
                for (int ks = 0; ks < 2; ++ks)                                  \
                    af[m2][ks] = *(const f16x8*)(sAc +                          \
                        (((wr << 6) + (((MB) + m2) << 4) + fr) << 7) +          \
                        (((ks << 6) + (quad << 4)) ^ axor));                    \
            __builtin_amdgcn_s_setprio(1);                                      \
            _Pragma("unroll")                                                   \
            for (int ks = 0; ks < 2; ++ks)                                      \
                _Pragma("unroll")                                               \
                for (int m2 = 0; m2 < 2; ++m2)                                  \
                    _Pragma("unroll")                                           \
                    for (int ni = 0; ni < 4; ++ni)                              \
                        acc[(MB) + m2][ni] = __builtin_amdgcn_mfma_f32_16x16x32_f16( \
                            af[m2][ks], bfr[ni][ks], acc[(MB) + m2][ni], 0, 0, 0); \
            __builtin_amdgcn_s_setprio(0);                                      \
        }                                                                       \
        __builtin_amdgcn_sched_barrier(0);                                      \
        __builtin_amdgcn_s_barrier();                                           \
        __builtin_amdgcn_sched_barrier(0);

    for (int kt = 0; kt < 32; ++kt) {
        const int cur = kt & 1;
        const char* sAc = (const char*)sA + (cur << 14);
        const char* sBc = (const char*)sB + (cur << 15);
        const bool pf = (kt < 30);

        f16x8 bfr[4][2];
#pragma unroll
        for (int ni = 0; ni < 4; ++ni) {
            const int brow = (wc << 6) + (ni << 4) + fr;
#pragma unroll
            for (int ks = 0; ks < 2; ++ks)
                bfr[ni][ks] = *(const f16x8*)(sBc + brow * 128 +
                    (((ks << 6) + (quad << 4)) ^ axor));
        }
        QPHASE(0)
        if (pf) { QSB(cur, kt + 2, 0); QSB(cur, kt + 2, 1);
                  QSB(cur, kt + 2, 2); QSB(cur, kt + 2, 3); }
        QPHASE(2)
        if (pf) {
            QSA(cur, kt + 2, 0); QSA(cur, kt + 2, 1);
            asm volatile("s_waitcnt vmcnt(6)" ::: "memory");
        } else {
            asm volatile("s_waitcnt vmcnt(0)" ::: "memory");
        }
        __builtin_amdgcn_sched_barrier(0);
        __builtin_amdgcn_s_barrier();
        __builtin_amdgcn_sched_barrier(0);
    }
#undef QPHASE
#undef QSA
#undef QSB
#undef QG

#pragma unroll
    for (int mi = 0; mi < 4; ++mi)
#pragma unroll
        for (int ni = 0; ni < 4; ++ni) {
            const int col = n0 + (wc << 6) + (ni << 4) + fr;
            const float bv = bias[col];
#pragma unroll
            for (int r = 0; r < 4; ++r) {
                const int rowg = m0 + (wr << 6) + (mi << 4) + (quad << 2) + r;
                C[(size_t)rowg * DIM + col] = acc[mi][ni][r] + bv;
            }
        }
}

// ===================================================================== GEMM (fp32 fallback)
#define BM 64
#define BN 64
#define BK 16

__global__ __launch_bounds__(256) void gemm_nt_kernel(
    const float* __restrict__ A, const float* __restrict__ W,
    const float* __restrict__ bias, float* __restrict__ C,
    const int M, const int N, const int K)
{
    __shared__ float As[BK][BM + 4];
    __shared__ float Bs[BK][BN + 4];
    const int tid = threadIdx.x;
    const int tx = tid & 15;
    const int ty = tid >> 4;
    const int m0 = blockIdx.y * BM;
    const int n0 = blockIdx.x * BN;
    const int ldr = tid >> 2;
    const int ldc = (tid & 3) << 2;

    float acc[4][4] = {};

    for (int k0 = 0; k0 < K; k0 += BK) {
        __syncthreads();
        const float4 av = *(const float4*)&A[(size_t)(m0 + ldr) * K + (k0 + ldc)];
        const float4 wv = *(const float4*)&W[(size_t)(n0 + ldr) * K + (k0 + ldc)];
        As[ldc + 0][ldr] = av.x; As[ldc + 1][ldr] = av.y;
        As[ldc + 2][ldr] = av.z; As[ldc + 3][ldr] = av.w;
        Bs[ldc + 0][ldr] = wv.x; Bs[ldc + 1][ldr] = wv.y;
        Bs[ldc + 2][ldr] = wv.z; Bs[ldc + 3][ldr] = wv.w;
        __syncthreads();
#pragma unroll
        for (int k = 0; k < BK; ++k) {
            const float4 a4 = *(const float4*)&As[k][ty << 2];
            const float4 b4 = *(const float4*)&Bs[k][tx << 2];
            const float aa[4] = {a4.x, a4.y, a4.z, a4.w};
            const float bb[4] = {b4.x, b4.y, b4.z, b4.w};
#pragma unroll
            for (int i = 0; i < 4; ++i)
#pragma unroll
                for (int j = 0; j < 4; ++j)
                    acc[i][j] = fmaf(aa[i], bb[j], acc[i][j]);
        }
    }

#pragma unroll
    for (int i = 0; i < 4; ++i) {
        const int row = m0 + (ty << 2) + i;
        const int col = n0 + (tx << 2);
        float4 ov;
        ov.x = acc[i][0]; ov.y = acc[i][1]; ov.z = acc[i][2]; ov.w = acc[i][3];
        if (bias != nullptr) {
            ov.x += bias[col + 0]; ov.y += bias[col + 1];
            ov.z += bias[col + 2]; ov.w += bias[col + 3];
        }
        *(float4*)&C[(size_t)row * N + col] = ov;
    }
}

// ==================== fused RMS+RoPE for Q and K (fp16 in, bf16 out)
__global__ __launch_bounds__(256) void rmsnorm_rope_qk_kernel(
    const ushort_t* __restrict__ Qh, const float* __restrict__ gq,
    ushort_t* __restrict__ qbh,
    const ushort_t* __restrict__ Kh, const float* __restrict__ gk,
    ushort_t* __restrict__ kbh,
    const float* __restrict__ freqs)
{
    const int r = blockIdx.x;
    const int s = r & (SEQ - 1);
    const int tid = threadIdx.x;
    const int base = tid << 3;
    const bool isQ = (blockIdx.y == 0);
    const ushort_t* T = isQ ? Qh : Kh;
    const float* g = isQ ? gq : gk;
    ushort_t* out  = isQ ? qbh : kbh;
    const float posc = isQ ? 0.088388347648318447f : 1.0f;

    const uint4 raw = *(const uint4*)&T[(size_t)r * DIM + base];
    const ushort_t* rp = (const ushort_t*)&raw;
    float v[8];
#pragma unroll
    for (int i = 0; i < 8; ++i) v[i] = h2f(rp[i]);

    float ss = 0.f;
#pragma unroll
    for (int i = 0; i < 8; ++i) ss += v[i] * v[i];
#pragma unroll
    for (int off = 32; off > 0; off >>= 1) ss += __shfl_down(ss, off);

    __shared__ float wsum[4];
    __shared__ float inv_sh;
    if ((tid & 63) == 0) wsum[tid >> 6] = ss;
    __syncthreads();
    if (tid == 0)
        inv_sh = rsqrtf((wsum[0] + wsum[1] + wsum[2] + wsum[3]) * (1.0f / DIM) + EPS_RMS);
    __syncthreads();
    const float inv = inv_sh * posc;

    float gg[8];
    *(float4*)&gg[0] = *(const float4*)&g[base];
    *(float4*)&gg[4] = *(const float4*)&g[base + 4];
#pragma unroll
    for (int i = 0; i < 8; ++i) v[i] *= inv * gg[i];

    const int p0 = (base & (HD - 1)) >> 1;
#pragma unroll
    for (int pp = 0; pp < 4; ++pp) {
        float sn, cs;
        __sincosf(freqs[(size_t)s * (HD / 2) + p0 + pp], &sn, &cs);
        const float t0 = v[2 * pp], t1 = v[2 * pp + 1];
        v[2 * pp]     = t0 * cs - t1 * sn;
        v[2 * pp + 1] = t0 * sn + t1 * cs;
    }

    uint_t pk[4];
#pragma unroll
    for (int j = 0; j < 4; ++j)
        pk[j] = (uint_t)f2bf(v[2 * j]) | ((uint_t)f2bf(v[2 * j + 1]) << 16);
    *(uint4*)&out[(size_t)r * DIM + base] = make_uint4(pk[0], pk[1], pk[2], pk[3]);
}

// ================================== RMS + RoPE (fp32 in/out, fallback path)
__global__ __launch_bounds__(256) void rmsnorm_rope_kernel(
    float* __restrict__ T, const float* __restrict__ g,
    const float* __restrict__ freqs)
{
    const int r = blockIdx.x;
    const int s = r & (SEQ - 1);
    const int tid = threadIdx.x;
    const int base = tid << 3;

    float v[8];
    *(float4*)&v[0] = *(const float4*)&T[(size_t)r * DIM + base];
    *(float4*)&v[4] = *(const float4*)&T[(size_t)r * DIM + base + 4];

    float ss = 0.f;
#pragma unroll
    for (int i = 0; i < 8; ++i) ss += v[i] * v[i];
#pragma unroll
    for (int off = 32; off > 0; off >>= 1) ss += __shfl_down(ss, off);

    __shared__ float wsum[4];
    __shared__ float inv_sh;
    if ((tid & 63) == 0) wsum[tid >> 6] = ss;
    __syncthreads();
    if (tid == 0)
        inv_sh = rsqrtf((wsum[0] + wsum[1] + wsum[2] + wsum[3]) * (1.0f / DIM) + EPS_RMS);
    __syncthreads();
    const float inv = inv_sh;

    float gg[8];
    *(float4*)&gg[0] = *(const float4*)&g[base];
    *(float4*)&gg[4] = *(const float4*)&g[base + 4];
#pragma unroll
    for (int i = 0; i < 8; ++i) v[i] *= inv * gg[i];

    const int p0 = (base & (HD - 1)) >> 1;
#pragma unroll
    for (int pp = 0; pp < 4; ++pp) {
        float sn, cs;
        __sincosf(freqs[(size_t)s * (HD / 2) + p0 + pp], &sn, &cs);
        const float t0 = v[2 * pp], t1 = v[2 * pp + 1];
        v[2 * pp]     = t0 * cs - t1 * sn;
        v[2 * pp + 1] = t0 * sn + t1 * cs;
    }

    *(float4*)&T[(size_t)r * DIM + base]     = *(float4*)&v[0];
    *(float4*)&T[(size_t)r * DIM + base + 4] = *(float4*)&v[4];
}

// ======================================================== MFMA flash attention
// Best-measured form (R4): LDS-staged K/V, 3 blocks/CU, XCD swizzle,
// T13 defer-max, T5 setprio.
#define AQ 128
#define AK 64
#define KSTR 136   // sK row stride (elems): 272 B
#define VSTR 72    // sVt/sP row stride (elems): 144 B
#define RESCALE_THR 8.0f

__global__ __launch_bounds__(256, 3) void attn_mfma_kernel(
    const ushort_t* __restrict__ QH, const ushort_t* __restrict__ KH,
    const ushort_t* __restrict__ VtG, const int* __restrict__ seq_lens,
    ushort_t* __restrict__ Oh)
{
    __shared__ __align__(16) ushort_t sK[AK * KSTR];    // [key][hd]
    __shared__ __align__(16) ushort_t sVt[HD * VSTR];   // [d][key]
    __shared__ __align__(16) ushort_t sP[AQ * VSTR];    // [query][key]

    const int tid  = threadIdx.x;
    const int w    = tid >> 6;
    const int lane = tid & 63;
    const int fr   = lane & 15;
    const int quad = lane >> 4;

    const int bid = blockIdx.x;
    const int sw  = (bid & 7) * 64 + (bid >> 3);
    const int q0  = (sw & 15) * AQ;
    const int hb  = sw >> 4;          // 0..31
    const int h   = hb & 15;
    const int b   = hb >> 4;
    const int len = seq_lens[b];

    bf16x8 qfrag[2][4];
#pragma unroll
    for (int qt = 0; qt < 2; ++qt)
#pragma unroll
        for (int h4 = 0; h4 < 4; ++h4) {
            const size_t qrow = (size_t)(b * SEQ + q0 + (w << 5) + (qt << 4) + fr);
            qfrag[qt][h4] = *(const bf16x8*)&QH[qrow * DIM + h * HD + (h4 << 5) + (quad << 3)];
        }

    f32x4 Oacc[2][8];
#pragma unroll
    for (int qt = 0; qt < 2; ++qt)
#pragma unroll
        for (int dt = 0; dt < 8; ++dt)
            Oacc[qt][dt] = (f32x4){0.f, 0.f, 0.f, 0.f};
    float mrow[2] = {-1.0e30f, -1.0e30f};
    float lrow[2] = {0.f, 0.f};

    const int kr  = tid >> 4;              // 0..15
    const int kc8 = (tid & 15) << 3;       // elem col in [0,128)
    const int vd  = tid >> 3;              // 0..31
    const int vc8 = (tid & 7) << 3;        // key col in [0,64)
    const size_t kbase = (size_t)(b * SEQ) * DIM + h * HD + kc8;
    const size_t vbase = ((size_t)(b * NH + h) * HD) * SEQ + vc8;

    const int ntiles = (len + AK - 1) / AK;
    for (int t = 0; t < ntiles; ++t) {
        const int k0 = t * AK;
        const bool masked = (k0 + AK > len);   // wave-uniform
        __syncthreads();
        {
            uint4 kv[4], vv[4];
#pragma unroll
            for (int j = 0; j < 4; ++j)
                kv[j] = *(const uint4*)&KH[kbase + (size_t)(k0 + kr + (j << 4)) * DIM];
#pragma unroll
            for (int j = 0; j < 4; ++j)
                vv[j] = *(const uint4*)&VtG[vbase + (size_t)(vd + (j << 5)) * SEQ + k0];
#pragma unroll
            for (int j = 0; j < 4; ++j)
                *(uint4*)&sK[(kr + (j << 4)) * KSTR + kc8] = kv[j];
#pragma unroll
            for (int j = 0; j < 4; ++j)
                *(uint4*)&sVt[(vd + (j << 5)) * VSTR + vc8] = vv[j];
        }
        __syncthreads();

        f32x4 S[4][2];
        __builtin_amdgcn_s_setprio(1);
#pragma unroll
        for (int kt = 0; kt < 4; ++kt) {
            bf16x8 kf[4];
#pragma unroll
            for (int h4 = 0; h4 < 4; ++h4)
                kf[h4] = *(const bf16x8*)&sK[((kt << 4) + fr) * KSTR + (h4 << 5) + (quad << 3)];
#pragma unroll
            for (int qt = 0; qt < 2; ++qt) {
                f32x4 a = (f32x4){0.f, 0.f, 0.f, 0.f};
#pragma unroll
                for (int h4 = 0; h4 < 4; ++h4)
                    a = __builtin_amdgcn_mfma_f32_16x16x32_bf16(kf[h4], qfrag[qt][h4], a, 0, 0, 0);
                S[kt][qt] = a;
            }
        }
        __builtin_amdgcn_s_setprio(0);

#pragma unroll
        for (int qt = 0; qt < 2; ++qt) {
            float tm = -1.0e30f;
            if (masked) {
#pragma unroll
                for (int kt = 0; kt < 4; ++kt)
#pragma unroll
                    for (int r = 0; r < 4; ++r) {
                        const int key = k0 + (kt << 4) + (quad << 2) + r;
                        float s = (key < len) ? S[kt][qt][r] : -1.0e30f;
                        S[kt][qt][r] = s;
                        tm = fmaxf(tm, s);
                    }
            } else {
#pragma unroll
                for (int kt = 0; kt < 4; ++kt)
#pragma unroll
                    for (int r = 0; r < 4; ++r)
                        tm = fmaxf(tm, S[kt][qt][r]);
            }
            tm = fmaxf(tm, __shfl_xor(tm, 16));
            tm = fmaxf(tm, __shfl_xor(tm, 32));

            float mnew;
            if (__all(tm - mrow[qt] <= RESCALE_THR)) {
                mnew = mrow[qt];
            } else {
                mnew = fmaxf(mrow[qt], tm);
                const float alpha = __expf(mrow[qt] - mnew);
                mrow[qt] = mnew;
                lrow[qt] *= alpha;
#pragma unroll
                for (int r = 0; r < 4; ++r) {
                    const float ar = __shfl(alpha, (quad << 2) + r);
#pragma unroll
                    for (int dt = 0; dt < 8; ++dt)
                        Oacc[qt][dt][r] *= ar;
                }
            }

            float rsum = 0.f;
#pragma unroll
            for (int kt = 0; kt < 4; ++kt) {
                float p[4];
#pragma unroll
                for (int r = 0; r < 4; ++r) {
                    p[r] = __expf(S[kt][qt][r] - mnew);
                    rsum += p[r];
                }
                uint2 pk;
                pk.x = (uint_t)f2bf(p[0]) | ((uint_t)f2bf(p[1]) << 16);
                pk.y = (uint_t)f2bf(p[2]) | ((uint_t)f2bf(p[3]) << 16);
                *(uint2*)&sP[((w << 5) + (qt << 4) + fr) * VSTR + (kt << 4) + (quad << 2)] = pk;
            }
            rsum += __shfl_xor(rsum, 16);
            rsum += __shfl_xor(rsum, 32);
            lrow[qt] += rsum;
        }

        __builtin_amdgcn_s_setprio(1);
#pragma unroll
        for (int ks = 0; ks < 2; ++ks) {
            bf16x8 pf[2];
#pragma unroll
            for (int qt = 0; qt < 2; ++qt)
                pf[qt] = *(const bf16x8*)&sP[((w << 5) + (qt << 4) + fr) * VSTR + (ks << 5) + (quad << 3)];
#pragma unroll
            for (int dt = 0; dt < 8; ++dt) {
                const bf16x8 vf = *(const bf16x8*)&sVt[((dt << 4) + fr) * VSTR + (ks << 5) + (quad << 3)];
#pragma unroll
                for (int qt = 0; qt < 2; ++qt)
                    Oacc[qt][dt] = __builtin_amdgcn_mfma_f32_16x16x32_bf16(pf[qt], vf, Oacc[qt][dt], 0, 0, 0);
            }
        }
        __builtin_amdgcn_s_setprio(0);
    }

    // ---- writeout (fp16, feeds final GEMM A-side directly)
#pragma unroll
    for (int qt = 0; qt < 2; ++qt) {
        float linv[4];
#pragma unroll
        for (int r = 0; r < 4; ++r)
            linv[r] = 1.0f / __shfl(lrow[qt], (quad << 2) + r);
#pragma unroll
        for (int dt = 0; dt < 8; ++dt)
#pragma unroll
            for (int r = 0; r < 4; ++r) {
                const int qrow = q0 + (w << 5) + (qt << 4) + (quad << 2) + r;
                Oh[(size_t)(b * SEQ + qrow) * DIM + h * HD + (dt << 4) + fr] =
                    f2h(Oacc[qt][dt][r] * linv[r]);
            }
    }
}

// ======================================== fp32 flash attention (fallback)
#define BQ  64
#define BKT 64

__global__ __launch_bounds__(256) void attn_kernel(
    const float* __restrict__ Q, const float* __restrict__ K,
    const float* __restrict__ V, const int* __restrict__ seq_lens,
    float* __restrict__ O)
{
    const int qt = blockIdx.x;
    const int h  = blockIdx.y;
    const int b  = blockIdx.z;
    const int len = seq_lens[b];
    const int q0 = qt * BQ;
    const float scale = 0.088388347648318447f;

    __shared__ float Qst[HD][BQ + 4];
    __shared__ float Kst[HD][BKT + 4];
    __shared__ float Vs[BKT][HD + 4];
    __shared__ float Sc[BQ][BKT + 1];
    __shared__ float mrow[BQ], lrow[BQ], alpha_s[BQ];

    const int tid = threadIdx.x;
    const int si0 = (tid >> 4) << 2;
    const int sj0 = (tid & 15) << 2;
    const int pi0 = (tid >> 4) << 2;
    const int pc0 = (tid & 15) << 3;

    for (int i = tid; i < BQ * HD / 4; i += 256) {
        const int e = i << 2;
        const int row = e >> 7;
        const int c0 = e & (HD - 1);
        const float4 qv = *(const float4*)&Q[(size_t)(b * SEQ + q0 + row) * DIM + h * HD + c0];
        Qst[c0 + 0][row] = qv.x; Qst[c0 + 1][row] = qv.y;
        Qst[c0 + 2][row] = qv.z; Qst[c0 + 3][row] = qv.w;
    }
    if (tid < BQ) { mrow[tid] = -3.0e38f; lrow[tid] = 0.f; }

    float o[4][8] = {};
    __syncthreads();

    const int ntiles = (len + BKT - 1) / BKT;
    for (int t = 0; t < ntiles; ++t) {
        const int k0 = t * BKT;
        __syncthreads();
        for (int i = tid; i < BKT * HD / 4; i += 256) {
            const int e = i << 2;
            const int row = e >> 7;
            const int c0 = e & (HD - 1);
            const int kg = k0 + row;
            float4 kv = make_float4(0.f, 0.f, 0.f, 0.f);
            float4 vv = make_float4(0.f, 0.f, 0.f, 0.f);
            if (kg < len) {
                kv = *(const float4*)&K[(size_t)(b * SEQ + kg) * DIM + h * HD + c0];
                vv = *(const float4*)&V[(size_t)(b * SEQ + kg) * DIM + h * HD + c0];
            }
            Kst[c0 + 0][row] = kv.x; Kst[c0 + 1][row] = kv.y;
            Kst[c0 + 2][row] = kv.z; Kst[c0 + 3][row] = kv.w;
            *(float4*)&Vs[row][c0] = vv;
        }
        __syncthreads();

        float acc[4][4] = {};
#pragma unroll 8
        for (int kk = 0; kk < HD; ++kk) {
            const float4 q4 = *(const float4*)&Qst[kk][si0];
            const float4 k4 = *(const float4*)&Kst[kk][sj0];
            const float qa[4] = {q4.x, q4.y, q4.z, q4.w};
            const float ka[4] = {k4.x, k4.y, k4.z, k4.w};
#pragma unroll
            for (int i = 0; i < 4; ++i)
#pragma unroll
                for (int j = 0; j < 4; ++j)
                    acc[i][j] = fmaf(qa[i], ka[j], acc[i][j]);
        }
#pragma unroll
        for (int i = 0; i < 4; ++i)
#pragma unroll
            for (int j = 0; j < 4; ++j) {
                const int jg = k0 + sj0 + j;
                Sc[si0 + i][sj0 + j] = (jg < len) ? acc[i][j] * scale : -1.0e9f;
            }
        __syncthreads();

        if (tid < BQ) {
            const int i = tid;
            const float m_old = mrow[i];
            float mx = m_old;
            for (int j = 0; j < BKT; ++j) mx = fmaxf(mx, Sc[i][j]);
            const float al = __expf(m_old - mx);
            float sum = 0.f;
            for (int j = 0; j < BKT; ++j) {
                const float p = __expf(Sc[i][j] - mx);
                Sc[i][j] = p;
                sum += p;
            }
            mrow[i] = mx;
            lrow[i] = lrow[i] * al + sum;
            alpha_s[i] = al;
        }
        __syncthreads();

#pragma unroll
        for (int i = 0; i < 4; ++i) {
            const float al = alpha_s[pi0 + i];
#pragma unroll
            for (int c = 0; c < 8; ++c) o[i][c] *= al;
        }
        for (int j = 0; j < BKT; ++j) {
            float p[4];
#pragma unroll
            for (int i = 0; i < 4; ++i) p[i] = Sc[pi0 + i][j];
            const float4 v0 = *(const float4*)&Vs[j][pc0];
            const float4 v1 = *(const float4*)&Vs[j][pc0 + 4];
            const float va[8] = {v0.x, v0.y, v0.z, v0.w, v1.x, v1.y, v1.z, v1.w};
#pragma unroll
            for (int i = 0; i < 4; ++i)
#pragma unroll
                for (int c = 0; c < 8; ++c)
                    o[i][c] = fmaf(p[i], va[c], o[i][c]);
        }
    }

#pragma unroll
    for (int i = 0; i < 4; ++i) {
        const float invl = 1.0f / lrow[pi0 + i];
        float4 w0, w1;
        w0.x = o[i][0] * invl; w0.y = o[i][1] * invl;
        w0.z = o[i][2] * invl; w0.w = o[i][3] * invl;
        w1.x = o[i][4] * invl; w1.y = o[i][5] * invl;
        w1.z = o[i][6] * invl; w1.w = o[i][7] * invl;
        float* op = &O[(size_t)(b * SEQ + q0 + pi0 + i) * DIM + h * HD + pc0];
        *(float4*)&op[0] = w0;
        *(float4*)&op[4] = w1;
    }
}

// ==================================================================== launch
extern "C" void kernel_launch(void* const* d_in, const int* in_sizes, int n_in,
                              void* d_out, int out_size, void* d_ws, size_t ws_size,
                              hipStream_t stream)
{
    const float* x        = (const float*)d_in[0];
    const int*   seq_lens = (const int*)d_in[1];
    const float* freqs    = (const float*)d_in[3];
    const float* Wq       = (const float*)d_in[4];
    const float* Wk       = (const float*)d_in[5];
    const float* Wv       = (const float*)d_in[6];
    const float* Wo       = (const float*)d_in[7];
    const float* bo       = (const float*)d_in[8];
    const float* gq       = (const float*)d_in[9];
    const float* gk       = (const float*)d_in[10];
    float* out = (float*)d_out;

    const size_t mat = (size_t)NROWS * DIM;       // 8.39M elems
    const size_t wsz = (size_t)DIM * DIM;         // 4.19M elems

    // ---- MFMA-path workspace layout (fp16 Q/K; layout superset of old) ----
    ushort_t* qh16 = (ushort_t*)d_ws;              // mat fp16 (Q pre-norm)
    ushort_t* kh16 = qh16 + mat;                   // mat fp16 (K pre-norm)
    ushort_t* xh   = kh16 + 3 * mat;               // keep old offsets
    ushort_t* wqh  = xh + mat;                     // 4 x wsz fp16 weights
    ushort_t* wkh  = wqh + wsz;
    ushort_t* wvh  = wkh + wsz;
    ushort_t* woh  = wvh + wsz;
    ushort_t* qbh  = woh + wsz;                    // mat bf16 (Q, pre-scaled)
    ushort_t* kbh  = qbh + mat;                    // mat bf16
    ushort_t* vtg  = kbh + mat;                    // mat bf16 (transposed V)
    ushort_t* abh  = vtg + mat;                    // mat fp16 (attn out)

    const size_t need = 2 * mat * sizeof(float)
                      + (mat + 4 * wsz + 4 * mat) * sizeof(ushort_t);

    if (ws_size >= need) {
        // ================= plain-fp16 MFMA path =================
        cvt_all_kernel<<<12288, 256, 0, stream>>>(
            x, Wq, Wk, Wv, Wo, xh, wqh, wkh, wvh, woh);

        qkv_gemm_kernel<<<768, 512, 0, stream>>>(xh, wqh, wkh, wvh, qh16, kh16, vtg);

        rmsnorm_rope_qk_kernel<<<dim3(NROWS, 2), 256, 0, stream>>>(
            qh16, gq, qbh, kh16, gk, kbh, freqs);

        attn_mfma_kernel<<<512, 256, 0, stream>>>(qbh, kbh, vtg, seq_lens, abh);

        wo_gemm_kernel<<<256, 512, 0, stream>>>(abh, woh, bo, out);
    } else {
        // ================= fp32 fallback (134 MB) =================
        float* Qb = (float*)d_ws;
        float* Kb = Qb + mat;
        float* Vb = Kb + mat;
        float* Ab = Vb + mat;
        const dim3 gemm_grid(DIM / BN, NROWS / BM);
        gemm_nt_kernel<<<gemm_grid, 256, 0, stream>>>(x, Wq, nullptr, Qb, NROWS, DIM, DIM);
        gemm_nt_kernel<<<gemm_grid, 256, 0, stream>>>(x, Wk, nullptr, Kb, NROWS, DIM, DIM);
        gemm_nt_kernel<<<gemm_grid, 256, 0, stream>>>(x, Wv, nullptr, Vb, NROWS, DIM, DIM);
        rmsnorm_rope_kernel<<<NROWS, 256, 0, stream>>>(Qb, gq, freqs);
        rmsnorm_rope_kernel<<<NROWS, 256, 0, stream>>>(Kb, gk, freqs);
        attn_kernel<<<dim3(SEQ / BQ, NH, BATCH), 256, 0, stream>>>(Qb, Kb, Vb, seq_lens, Ab);
        gemm_nt_kernel<<<gemm_grid, 256, 0, stream>>>(Ab, Wo, bo, out, NROWS, DIM, DIM);
    }
}